// Round 2
// baseline (40992.755 us; speedup 1.0000x reference)
//
#include <hip/hip_runtime.h>

typedef unsigned short u16;
typedef unsigned int u32;
typedef u16 u16x8 __attribute__((ext_vector_type(8)));
typedef u16 u16x4 __attribute__((ext_vector_type(4)));
typedef __bf16 bf16x8 __attribute__((ext_vector_type(8)));
typedef float f32x4 __attribute__((ext_vector_type(4)));

#define B_ 64
#define T_ 256
#define D_ 256
#define H_ 1024
#define G4 4096
#define TC 64            // timesteps per chunk
#define MC 4096          // rows per chunk (B_*TC)
#define NCHUNK 4

// ---------- helpers ----------
__device__ __forceinline__ u16 f2bf(float x) {
  u32 u = __builtin_bit_cast(u32, x);
  u += 0x7fffu + ((u >> 16) & 1u);
  return (u16)(u >> 16);
}
__device__ __forceinline__ float bf2f(u16 h) {
  u32 u = ((u32)h) << 16;
  return __builtin_bit_cast(float, u);
}
__device__ __forceinline__ float sigmoidf_(float x) { return 1.f / (1.f + __expf(-x)); }

__device__ __forceinline__ f32x4 mfma16(u16x8 a, u16x8 b, f32x4 c) {
  return __builtin_amdgcn_mfma_f32_16x16x32_bf16(
      __builtin_bit_cast(bf16x8, a), __builtin_bit_cast(bf16x8, b), c, 0, 0, 0);
}

__device__ __forceinline__ void gl2lds16(const u16* g, u16* l) {
  __builtin_amdgcn_global_load_lds(
      (const __attribute__((address_space(1))) u32*)(const void*)g,
      (__attribute__((address_space(3))) u32*)(void*)l, 16, 0, 0);
}

// ---------- split fp32 -> (hi, lo) bf16 planes ----------
__global__ void k_split(const float* __restrict__ src, u16* __restrict__ hi,
                        u16* __restrict__ lo, int n4) {
  int i = blockIdx.x * 256 + threadIdx.x;
  if (i >= n4) return;
  const float4* s4 = (const float4*)src;
  float4 v = s4[i];
  u16 h0 = f2bf(v.x), h1 = f2bf(v.y), h2 = f2bf(v.z), h3 = f2bf(v.w);
  u16x4 hv = {h0, h1, h2, h3};
  u16x4 lv = {f2bf(v.x - bf2f(h0)), f2bf(v.y - bf2f(h1)),
              f2bf(v.z - bf2f(h2)), f2bf(v.w - bf2f(h3))};
  *(u16x4*)(hi + 4 * (size_t)i) = hv;
  *(u16x4*)(lo + 4 * (size_t)i) = lv;
}

// gather one time-chunk of xx ([B,T,D] -> [B*TC, D]) and split planes
__global__ void k_split_x(const float* __restrict__ xx, u16* __restrict__ hi,
                          u16* __restrict__ lo, int t0) {
  int i = blockIdx.x * 256 + threadIdx.x;   // over MC * D_/4
  if (i >= MC * (D_ / 4)) return;
  int row = i >> 6, c4 = i & 63;
  int b = row >> 6, tc = row & 63;
  const float4* s4 = (const float4*)xx;
  float4 v = s4[(size_t)(b * T_ + t0 + tc) * (D_ / 4) + c4];
  u16 h0 = f2bf(v.x), h1 = f2bf(v.y), h2 = f2bf(v.z), h3 = f2bf(v.w);
  u16x4 hv = {h0, h1, h2, h3};
  u16x4 lv = {f2bf(v.x - bf2f(h0)), f2bf(v.y - bf2f(h1)),
              f2bf(v.z - bf2f(h2)), f2bf(v.w - bf2f(h3))};
  *(u16x4*)(hi + 4 * (size_t)i) = hv;
  *(u16x4*)(lo + 4 * (size_t)i) = lv;
}

__global__ void k_addvec(const float* __restrict__ a, const float* __restrict__ b,
                         float* __restrict__ o, int n) {
  int i = blockIdx.x * 256 + threadIdx.x;
  if (i < n) o[i] = a[i] + b[i];
}

// ---------- split-precision GEMM: C[M,N] = A[M,K] * B[N,K]^T + bias (fp32 out) ----
__global__ __launch_bounds__(256, 2) void k_gemm3(
    const u16* __restrict__ Ah, const u16* __restrict__ Al,
    const u16* __restrict__ Bh, const u16* __restrict__ Bl,
    const float* __restrict__ bias, float* __restrict__ C,
    int M, int N, int K)
{
  __shared__ __attribute__((aligned(16))) u16 sAh[4096];
  __shared__ __attribute__((aligned(16))) u16 sAl[4096];
  __shared__ __attribute__((aligned(16))) u16 sBh[4096];
  __shared__ __attribute__((aligned(16))) u16 sBl[4096];

  const int tid = threadIdx.x;
  const int lane = tid & 63;
  const int wv = tid >> 6;
  const int wm = wv & 1, wn = wv >> 1;
  const int m0 = blockIdx.x * 128;
  const int n0 = blockIdx.y * 128;

  const int r0 = tid >> 2;
  const int kg = (tid & 3) ^ (r0 & 3);
  const size_t aoff0 = (size_t)(m0 + r0) * K + kg * 8;
  const size_t aoff1 = (size_t)(m0 + r0 + 64) * K + kg * 8;
  const size_t boff0 = (size_t)(n0 + r0) * K + kg * 8;
  const size_t boff1 = (size_t)(n0 + r0 + 64) * K + kg * 8;
  const int lb0 = wv * 512;
  const int lb1 = 2048 + wv * 512;

  const int l15 = lane & 15, l4 = lane >> 4;
  int afo[4], bfo[4];
#pragma unroll
  for (int mt = 0; mt < 4; ++mt) {
    int r = wm * 64 + mt * 16 + l15;
    afo[mt] = (r * 4 + (l4 ^ (r & 3))) * 8;
  }
#pragma unroll
  for (int nt = 0; nt < 4; ++nt) {
    int r = wn * 64 + nt * 16 + l15;
    bfo[nt] = (r * 4 + (l4 ^ (r & 3))) * 8;
  }

  f32x4 acc[4][4] = {};

  for (int k0 = 0; k0 < K; k0 += 32) {
    __syncthreads();
    gl2lds16(Ah + aoff0 + k0, &sAh[lb0]);
    gl2lds16(Ah + aoff1 + k0, &sAh[lb1]);
    gl2lds16(Al + aoff0 + k0, &sAl[lb0]);
    gl2lds16(Al + aoff1 + k0, &sAl[lb1]);
    gl2lds16(Bh + boff0 + k0, &sBh[lb0]);
    gl2lds16(Bh + boff1 + k0, &sBh[lb1]);
    gl2lds16(Bl + boff0 + k0, &sBl[lb0]);
    gl2lds16(Bl + boff1 + k0, &sBl[lb1]);
    __syncthreads();

    u16x8 a_h[4], a_l[4], b_h[4], b_l[4];
#pragma unroll
    for (int i = 0; i < 4; ++i) {
      a_h[i] = *(const u16x8*)&sAh[afo[i]];
      a_l[i] = *(const u16x8*)&sAl[afo[i]];
      b_h[i] = *(const u16x8*)&sBh[bfo[i]];
      b_l[i] = *(const u16x8*)&sBl[bfo[i]];
    }
#pragma unroll
    for (int mt = 0; mt < 4; ++mt)
#pragma unroll
      for (int nt = 0; nt < 4; ++nt) {
        acc[mt][nt] = mfma16(a_h[mt], b_h[nt], acc[mt][nt]);
        acc[mt][nt] = mfma16(a_l[mt], b_h[nt], acc[mt][nt]);
        acc[mt][nt] = mfma16(a_h[mt], b_l[nt], acc[mt][nt]);
      }
  }

#pragma unroll
  for (int mt = 0; mt < 4; ++mt) {
    int mr = m0 + wm * 64 + mt * 16 + l4 * 4;
#pragma unroll
    for (int nt = 0; nt < 4; ++nt) {
      int nc = n0 + wn * 64 + nt * 16 + l15;
      float bv = bias[nc];
#pragma unroll
      for (int r = 0; r < 4; ++r)
        C[(size_t)(mr + r) * N + nc] = acc[mt][nt][r] + bv;
    }
  }
}

// ---------- l1 pointwise on one chunk ----------
__global__ void k_pw(const float* __restrict__ xg, u16* __restrict__ hhi,
                     u16* __restrict__ hlo) {
  int idx = blockIdx.x * 256 + threadIdx.x;  // MC*H_ threads
  int r = idx >> 10, j = idx & 1023;
  const float* g = xg + (size_t)r * G4;
  float cc = sigmoidf_(g[j]) * tanhf(g[2048 + j]);
  float h = sigmoidf_(g[3072 + j]) * tanhf(cc);
  u16 hh = f2bf(h);
  hhi[idx] = hh;
  hlo[idx] = f2bf(h - bf2f(hh));
}

// ---------- persistent recurrent LSTM, one time-chunk ----------
// 256 blocks x 256 threads; block owns 4 hidden units (16 gate cols).
// Whh fragments read from global (L2-resident). LDS only for gate gather (~4.4KB).
__global__ __launch_bounds__(256, 1) void k_rec(
    const float* __restrict__ xg,                     // [MC][4096] chunk gates (fp32)
    const u16* __restrict__ Whi, const u16* __restrict__ Wlo,  // [4096][1024]
    u16* __restrict__ hb_hi, u16* __restrict__ hb_lo, // [2][64][1024]
    float* __restrict__ cb,                           // [64][1024]
    u16* __restrict__ hs_hi, u16* __restrict__ hs_lo, // [MC][1024] or null
    float* __restrict__ hfinal,                       // [64][1024] or null
    u32* __restrict__ bar, int t0)
{
  __shared__ float sc[64 * 17 + 16];

  const int tid = threadIdx.x;
  const int lane = tid & 63, wv = tid >> 6;
  const int l15 = lane & 15, l4 = lane >> 4;
  const int u0 = blockIdx.x * 4;

  // B fragment: col n (=l15) -> gate n>>2, unit n&3 -> Whh row (n>>2)*1024 + u0 + (n&3)
  const int brow = (l15 >> 2) * 1024 + u0 + (l15 & 3);
  const u16* bph = Whi + (size_t)brow * 1024 + l4 * 8;
  const u16* bpl = Wlo + (size_t)brow * 1024 + l4 * 8;
  const int a_off = (wv * 16 + l15) * 1024 + l4 * 8;

  const int cb_i = (tid >> 2) * 1024 + u0 + (tid & 3);
  float c = cb[cb_i];

  u32 round = 0;
  for (int tt = 0; tt < TC; ++tt) {
    const int t = t0 + tt;
    const int rb = (t & 1) << 16;   // read h_{t-1}
    const int wb = 65536 - rb;      // write h_t
    f32x4 accA = {}, accB = {};
#pragma unroll
    for (int kc = 0; kc < 32; kc += 2) {
      int ka = rb + a_off + kc * 32;
      u16x8 ah0 = *(const u16x8*)(hb_hi + ka);
      u16x8 al0 = *(const u16x8*)(hb_lo + ka);
      u16x8 ah1 = *(const u16x8*)(hb_hi + ka + 32);
      u16x8 al1 = *(const u16x8*)(hb_lo + ka + 32);
      u16x8 bh0 = *(const u16x8*)(bph + kc * 32);
      u16x8 bl0 = *(const u16x8*)(bpl + kc * 32);
      u16x8 bh1 = *(const u16x8*)(bph + kc * 32 + 32);
      u16x8 bl1 = *(const u16x8*)(bpl + kc * 32 + 32);
      accA = mfma16(ah0, bh0, accA);
      accA = mfma16(al0, bh0, accA);
      accA = mfma16(ah0, bl0, accA);
      accB = mfma16(ah1, bh1, accB);
      accB = mfma16(al1, bh1, accB);
      accB = mfma16(ah1, bl1, accB);
    }
    f32x4 acc = accA + accB;
#pragma unroll
    for (int r = 0; r < 4; ++r)
      sc[(wv * 16 + l4 * 4 + r) * 17 + l15] = acc[r];
    __syncthreads();
    {
      int b = tid >> 2, j = tid & 3;
      const float* srow = sc + b * 17;
      size_t xo = (size_t)(b * TC + tt) * G4 + u0 + j;
      float gi = srow[j] + xg[xo];
      float gf = srow[4 + j] + xg[xo + 1024];
      float gg = srow[8 + j] + xg[xo + 2048];
      float go = srow[12 + j] + xg[xo + 3072];
      c = sigmoidf_(gf) * c + sigmoidf_(gi) * tanhf(gg);
      float h = sigmoidf_(go) * tanhf(c);
      u16 hh = f2bf(h), hl = f2bf(h - bf2f(hh));
      int ho = b * 1024 + u0 + j;
      hb_hi[wb + ho] = hh;
      hb_lo[wb + ho] = hl;
      if (hs_hi) {
        size_t so = (size_t)(b * TC + tt) * 1024 + u0 + j;
        hs_hi[so] = hh;
        hs_lo[so] = hl;
      }
      if (hfinal && t == T_ - 1) hfinal[ho] = h;
    }
    // ---- grid barrier: monotonic generation, no counter reset ----
    ++round;
    __threadfence();
    __syncthreads();
    if (tid == 0) {
      u32 a = __hip_atomic_fetch_add(&bar[0], 1u, __ATOMIC_ACQ_REL, __HIP_MEMORY_SCOPE_AGENT);
      if (a == 256u * round - 1u) {
        __hip_atomic_store(&bar[1], round, __ATOMIC_RELEASE, __HIP_MEMORY_SCOPE_AGENT);
      } else {
        while (__hip_atomic_load(&bar[1], __ATOMIC_ACQUIRE, __HIP_MEMORY_SCOPE_AGENT) < round)
          __builtin_amdgcn_s_sleep(1);
      }
    }
    __syncthreads();
    __threadfence();
  }
  cb[cb_i] = c;
}

// ---------- MLP (fp32 vector) ----------
__global__ void k_fc(const float* __restrict__ in, const float* __restrict__ W,
                     const float* __restrict__ bias, float* __restrict__ out,
                     int K, int N, int relu) {
  int b = blockIdx.x;
  int n = blockIdx.y * 256 + threadIdx.x;
  if (n >= N) return;
  const float4* wr = (const float4*)(W + (size_t)n * K);
  const float4* xr = (const float4*)(in + (size_t)b * K);
  float s = 0.f;
  for (int k = 0; k < K / 4; ++k) {
    float4 w = wr[k], x = xr[k];
    s += w.x * x.x + w.y * x.y + w.z * x.z + w.w * x.w;
  }
  s += bias[n];
  if (relu) s = fmaxf(s, 0.f);
  out[(size_t)b * N + n] = s;
}

__global__ void k_out(const float* __restrict__ z, const float* __restrict__ W3,
                      const float* __restrict__ b3, float* __restrict__ outp) {
  int b = blockIdx.x;
  int lane = threadIdx.x;  // 64
  const float4* wr = (const float4*)W3;
  const float4* xr = (const float4*)(z + b * 512);
  float s = 0.f;
  for (int k = lane; k < 128; k += 64) {
    float4 w = wr[k], x = xr[k];
    s += w.x * x.x + w.y * x.y + w.z * x.z + w.w * x.w;
  }
  for (int off = 32; off; off >>= 1) s += __shfl_down(s, off);
  if (lane == 0) outp[b] = s + b3[0];
}

// ---------- launch ----------
extern "C" void kernel_launch(void* const* d_in, const int* in_sizes, int n_in,
                              void* d_out, int out_size, void* d_ws, size_t ws_size,
                              hipStream_t stream) {
  (void)in_sizes; (void)n_in; (void)out_size; (void)ws_size;
  const float* xx  = (const float*)d_in[0];
  const float* W10 = (const float*)d_in[1];
  const float* b10i = (const float*)d_in[2];
  const float* b10h = (const float*)d_in[3];
  const float* W11 = (const float*)d_in[4];
  const float* b11i = (const float*)d_in[5];
  const float* b11h = (const float*)d_in[6];
  const float* W20 = (const float*)d_in[7];
  const float* Wh0 = (const float*)d_in[8];
  const float* b20i = (const float*)d_in[9];
  const float* b20h = (const float*)d_in[10];
  const float* W21 = (const float*)d_in[11];
  const float* Wh1 = (const float*)d_in[12];
  const float* b21i = (const float*)d_in[13];
  const float* b21h = (const float*)d_in[14];
  const float* mW1 = (const float*)d_in[15];
  const float* mb1 = (const float*)d_in[16];
  const float* mW2 = (const float*)d_in[17];
  const float* mb2 = (const float*)d_in[18];
  const float* mW3 = (const float*)d_in[19];
  const float* mb3 = (const float*)d_in[20];

  char* ws = (char*)d_ws;
  size_t o = 0;
  float* XG = (float*)(ws + o); o += (size_t)MC * G4 * 4;            // 64 MiB
  u16* Aah = (u16*)(ws + o); o += (size_t)MC * H_ * 2;               // ACT ping
  u16* Aal = (u16*)(ws + o); o += (size_t)MC * H_ * 2;
  u16* Abh = (u16*)(ws + o); o += (size_t)MC * H_ * 2;               // ACT pong
  u16* Abl = (u16*)(ws + o); o += (size_t)MC * H_ * 2;
  u16* XXh = (u16*)(ws + o); o += (size_t)MC * D_ * 2;
  u16* XXl = (u16*)(ws + o); o += (size_t)MC * D_ * 2;
  u16* W10h = (u16*)(ws + o); o += (size_t)G4 * D_ * 2;
  u16* W10l = (u16*)(ws + o); o += (size_t)G4 * D_ * 2;
  u16* W11h = (u16*)(ws + o); o += (size_t)G4 * H_ * 2;
  u16* W11l = (u16*)(ws + o); o += (size_t)G4 * H_ * 2;
  u16* W20h = (u16*)(ws + o); o += (size_t)G4 * H_ * 2;
  u16* W20l = (u16*)(ws + o); o += (size_t)G4 * H_ * 2;
  u16* Wh0h = (u16*)(ws + o); o += (size_t)G4 * H_ * 2;
  u16* Wh0l = (u16*)(ws + o); o += (size_t)G4 * H_ * 2;
  u16* W21h = (u16*)(ws + o); o += (size_t)G4 * H_ * 2;
  u16* W21l = (u16*)(ws + o); o += (size_t)G4 * H_ * 2;
  u16* Wh1h = (u16*)(ws + o); o += (size_t)G4 * H_ * 2;
  u16* Wh1l = (u16*)(ws + o); o += (size_t)G4 * H_ * 2;
  float* bs0 = (float*)(ws + o); o += G4 * 4;
  float* bs1 = (float*)(ws + o); o += G4 * 4;
  float* bs2 = (float*)(ws + o); o += G4 * 4;
  float* bs3 = (float*)(ws + o); o += G4 * 4;
  // state region (zeroed once per launch, contiguous)
  char* ST = ws + o;
  u16* hb0h = (u16*)(ws + o); o += 2 * B_ * H_ * 2;
  u16* hb0l = (u16*)(ws + o); o += 2 * B_ * H_ * 2;
  u16* hb1h = (u16*)(ws + o); o += 2 * B_ * H_ * 2;
  u16* hb1l = (u16*)(ws + o); o += 2 * B_ * H_ * 2;
  float* cb0 = (float*)(ws + o); o += B_ * H_ * 4;
  float* cb1 = (float*)(ws + o); o += B_ * H_ * 4;
  u32* BAR = (u32*)(ws + o); o += 8 * 64 * 4;
  size_t stBytes = (size_t)((ws + o) - ST);
  float* FH = (float*)(ws + o); o += B_ * H_ * 4;
  float* Z1 = (float*)(ws + o); o += B_ * H_ * 4;
  float* Z2 = (float*)(ws + o); o += B_ * 512 * 4;

  // --- one-time weight/bias prep ---
  k_split<<<(G4 * D_ / 4 + 255) / 256, 256, 0, stream>>>(W10, W10h, W10l, G4 * D_ / 4);
  k_split<<<(G4 * H_ / 4 + 255) / 256, 256, 0, stream>>>(W11, W11h, W11l, G4 * H_ / 4);
  k_split<<<(G4 * H_ / 4 + 255) / 256, 256, 0, stream>>>(W20, W20h, W20l, G4 * H_ / 4);
  k_split<<<(G4 * H_ / 4 + 255) / 256, 256, 0, stream>>>(Wh0, Wh0h, Wh0l, G4 * H_ / 4);
  k_split<<<(G4 * H_ / 4 + 255) / 256, 256, 0, stream>>>(W21, W21h, W21l, G4 * H_ / 4);
  k_split<<<(G4 * H_ / 4 + 255) / 256, 256, 0, stream>>>(Wh1, Wh1h, Wh1l, G4 * H_ / 4);
  k_addvec<<<16, 256, 0, stream>>>(b10i, b10h, bs0, G4);
  k_addvec<<<16, 256, 0, stream>>>(b11i, b11h, bs1, G4);
  k_addvec<<<16, 256, 0, stream>>>(b20i, b20h, bs2, G4);
  k_addvec<<<16, 256, 0, stream>>>(b21i, b21h, bs3, G4);
  hipMemsetAsync(ST, 0, stBytes, stream);

  dim3 gg(MC / 128, G4 / 128);
  const int pwBlocks = MC * H_ / 256;

  for (int c = 0; c < NCHUNK; ++c) {
    int t0 = c * TC;
    k_split_x<<<(MC * (D_ / 4) + 255) / 256, 256, 0, stream>>>(xx, XXh, XXl, t0);
    // l1 layer 0
    k_gemm3<<<gg, 256, 0, stream>>>(XXh, XXl, W10h, W10l, bs0, XG, MC, G4, D_);
    k_pw<<<pwBlocks, 256, 0, stream>>>(XG, Aah, Aal);
    // l1 layer 1
    k_gemm3<<<gg, 256, 0, stream>>>(Aah, Aal, W11h, W11l, bs1, XG, MC, G4, H_);
    k_pw<<<pwBlocks, 256, 0, stream>>>(XG, Abh, Abl);
    // l2 layer 0
    k_gemm3<<<gg, 256, 0, stream>>>(Abh, Abl, W20h, W20l, bs2, XG, MC, G4, H_);
    k_rec<<<256, 256, 0, stream>>>(XG, Wh0h, Wh0l, hb0h, hb0l, cb0,
                                   Aah, Aal, nullptr, BAR + (c * 2) * 64, t0);
    // l2 layer 1
    k_gemm3<<<gg, 256, 0, stream>>>(Aah, Aal, W21h, W21l, bs3, XG, MC, G4, H_);
    k_rec<<<256, 256, 0, stream>>>(XG, Wh1h, Wh1l, hb1h, hb1l, cb1,
                                   nullptr, nullptr, FH, BAR + (c * 2 + 1) * 64, t0);
  }

  // MLP
  k_fc<<<dim3(B_, 4), 256, 0, stream>>>(FH, mW1, mb1, Z1, H_, H_, 1);
  k_fc<<<dim3(B_, 2), 256, 0, stream>>>(Z1, mW2, mb2, Z2, H_, 512, 1);
  k_out<<<B_, 64, 0, stream>>>(Z2, mW3, mb3, (float*)d_out);
}

// Round 3
// 33963.693 us; speedup vs baseline: 1.2070x; 1.2070x over previous
//
#include <hip/hip_runtime.h>

typedef unsigned short u16;
typedef unsigned int u32;
typedef u16 u16x8 __attribute__((ext_vector_type(8)));
typedef u16 u16x4 __attribute__((ext_vector_type(4)));
typedef __bf16 bf16x8 __attribute__((ext_vector_type(8)));
typedef float f32x4 __attribute__((ext_vector_type(4)));

#define B_ 64
#define T_ 256
#define D_ 256
#define H_ 1024
#define G4 4096
#define TC 64            // timesteps per chunk
#define MC 4096          // rows per chunk (B_*TC)
#define NCHUNK 4
#define RBLK 64          // k_rec blocks (16 units each)

// ---------- helpers ----------
__device__ __forceinline__ u16 f2bf(float x) {
  u32 u = __builtin_bit_cast(u32, x);
  u += 0x7fffu + ((u >> 16) & 1u);
  return (u16)(u >> 16);
}
__device__ __forceinline__ float bf2f(u16 h) {
  u32 u = ((u32)h) << 16;
  return __builtin_bit_cast(float, u);
}
__device__ __forceinline__ float sigmoidf_(float x) { return 1.f / (1.f + __expf(-x)); }

__device__ __forceinline__ f32x4 mfma16(u16x8 a, u16x8 b, f32x4 c) {
  return __builtin_amdgcn_mfma_f32_16x16x32_bf16(
      __builtin_bit_cast(bf16x8, a), __builtin_bit_cast(bf16x8, b), c, 0, 0, 0);
}

__device__ __forceinline__ void gl2lds16(const u16* g, u16* l) {
  __builtin_amdgcn_global_load_lds(
      (const __attribute__((address_space(1))) u32*)(const void*)g,
      (__attribute__((address_space(3))) u32*)(void*)l, 16, 0, 0);
}

// ---------- split fp32 -> (hi, lo) bf16 planes ----------
__global__ void k_split(const float* __restrict__ src, u16* __restrict__ hi,
                        u16* __restrict__ lo, int n4) {
  int i = blockIdx.x * 256 + threadIdx.x;
  if (i >= n4) return;
  const float4* s4 = (const float4*)src;
  float4 v = s4[i];
  u16 h0 = f2bf(v.x), h1 = f2bf(v.y), h2 = f2bf(v.z), h3 = f2bf(v.w);
  u16x4 hv = {h0, h1, h2, h3};
  u16x4 lv = {f2bf(v.x - bf2f(h0)), f2bf(v.y - bf2f(h1)),
              f2bf(v.z - bf2f(h2)), f2bf(v.w - bf2f(h3))};
  *(u16x4*)(hi + 4 * (size_t)i) = hv;
  *(u16x4*)(lo + 4 * (size_t)i) = lv;
}

// gather one time-chunk of xx ([B,T,D] -> [B*TC, D]) and split planes
__global__ void k_split_x(const float* __restrict__ xx, u16* __restrict__ hi,
                          u16* __restrict__ lo, int t0) {
  int i = blockIdx.x * 256 + threadIdx.x;   // over MC * D_/4
  if (i >= MC * (D_ / 4)) return;
  int row = i >> 6, c4 = i & 63;
  int b = row >> 6, tc = row & 63;
  const float4* s4 = (const float4*)xx;
  float4 v = s4[(size_t)(b * T_ + t0 + tc) * (D_ / 4) + c4];
  u16 h0 = f2bf(v.x), h1 = f2bf(v.y), h2 = f2bf(v.z), h3 = f2bf(v.w);
  u16x4 hv = {h0, h1, h2, h3};
  u16x4 lv = {f2bf(v.x - bf2f(h0)), f2bf(v.y - bf2f(h1)),
              f2bf(v.z - bf2f(h2)), f2bf(v.w - bf2f(h3))};
  *(u16x4*)(hi + 4 * (size_t)i) = hv;
  *(u16x4*)(lo + 4 * (size_t)i) = lv;
}

__global__ void k_addvec(const float* __restrict__ a, const float* __restrict__ b,
                         float* __restrict__ o, int n) {
  int i = blockIdx.x * 256 + threadIdx.x;
  if (i < n) o[i] = a[i] + b[i];
}

// ---------- split-precision GEMM: C[M,N] = A[M,K] * B[N,K]^T + bias (fp32 out) ----
__global__ __launch_bounds__(256, 2) void k_gemm3(
    const u16* __restrict__ Ah, const u16* __restrict__ Al,
    const u16* __restrict__ Bh, const u16* __restrict__ Bl,
    const float* __restrict__ bias, float* __restrict__ C,
    int M, int N, int K)
{
  __shared__ __attribute__((aligned(16))) u16 sAh[4096];
  __shared__ __attribute__((aligned(16))) u16 sAl[4096];
  __shared__ __attribute__((aligned(16))) u16 sBh[4096];
  __shared__ __attribute__((aligned(16))) u16 sBl[4096];

  const int tid = threadIdx.x;
  const int lane = tid & 63;
  const int wv = tid >> 6;
  const int wm = wv & 1, wn = wv >> 1;
  const int m0 = blockIdx.x * 128;
  const int n0 = blockIdx.y * 128;

  const int r0 = tid >> 2;
  const int kg = (tid & 3) ^ (r0 & 3);
  const size_t aoff0 = (size_t)(m0 + r0) * K + kg * 8;
  const size_t aoff1 = (size_t)(m0 + r0 + 64) * K + kg * 8;
  const size_t boff0 = (size_t)(n0 + r0) * K + kg * 8;
  const size_t boff1 = (size_t)(n0 + r0 + 64) * K + kg * 8;
  const int lb0 = wv * 512;
  const int lb1 = 2048 + wv * 512;

  const int l15 = lane & 15, l4 = lane >> 4;
  int afo[4], bfo[4];
#pragma unroll
  for (int mt = 0; mt < 4; ++mt) {
    int r = wm * 64 + mt * 16 + l15;
    afo[mt] = (r * 4 + (l4 ^ (r & 3))) * 8;
  }
#pragma unroll
  for (int nt = 0; nt < 4; ++nt) {
    int r = wn * 64 + nt * 16 + l15;
    bfo[nt] = (r * 4 + (l4 ^ (r & 3))) * 8;
  }

  f32x4 acc[4][4] = {};

  for (int k0 = 0; k0 < K; k0 += 32) {
    __syncthreads();
    gl2lds16(Ah + aoff0 + k0, &sAh[lb0]);
    gl2lds16(Ah + aoff1 + k0, &sAh[lb1]);
    gl2lds16(Al + aoff0 + k0, &sAl[lb0]);
    gl2lds16(Al + aoff1 + k0, &sAl[lb1]);
    gl2lds16(Bh + boff0 + k0, &sBh[lb0]);
    gl2lds16(Bh + boff1 + k0, &sBh[lb1]);
    gl2lds16(Bl + boff0 + k0, &sBl[lb0]);
    gl2lds16(Bl + boff1 + k0, &sBl[lb1]);
    __syncthreads();

    u16x8 a_h[4], a_l[4], b_h[4], b_l[4];
#pragma unroll
    for (int i = 0; i < 4; ++i) {
      a_h[i] = *(const u16x8*)&sAh[afo[i]];
      a_l[i] = *(const u16x8*)&sAl[afo[i]];
      b_h[i] = *(const u16x8*)&sBh[bfo[i]];
      b_l[i] = *(const u16x8*)&sBl[bfo[i]];
    }
#pragma unroll
    for (int mt = 0; mt < 4; ++mt)
#pragma unroll
      for (int nt = 0; nt < 4; ++nt) {
        acc[mt][nt] = mfma16(a_h[mt], b_h[nt], acc[mt][nt]);
        acc[mt][nt] = mfma16(a_l[mt], b_h[nt], acc[mt][nt]);
        acc[mt][nt] = mfma16(a_h[mt], b_l[nt], acc[mt][nt]);
      }
  }

#pragma unroll
  for (int mt = 0; mt < 4; ++mt) {
    int mr = m0 + wm * 64 + mt * 16 + l4 * 4;
#pragma unroll
    for (int nt = 0; nt < 4; ++nt) {
      int nc = n0 + wn * 64 + nt * 16 + l15;
      float bv = bias[nc];
#pragma unroll
      for (int r = 0; r < 4; ++r)
        C[(size_t)(mr + r) * N + nc] = acc[mt][nt][r] + bv;
    }
  }
}

// ---------- l1 pointwise on one chunk ----------
__global__ void k_pw(const float* __restrict__ xg, u16* __restrict__ hhi,
                     u16* __restrict__ hlo) {
  int idx = blockIdx.x * 256 + threadIdx.x;  // MC*H_ threads
  int r = idx >> 10, j = idx & 1023;
  const float* g = xg + (size_t)r * G4;
  float cc = sigmoidf_(g[j]) * tanhf(g[2048 + j]);
  float h = sigmoidf_(g[3072 + j]) * tanhf(cc);
  u16 hh = f2bf(h);
  hhi[idx] = hh;
  hlo[idx] = f2bf(h - bf2f(hh));
}

// ---------- persistent recurrent LSTM, one time-chunk ----------
// RBLK=64 blocks x 512 threads (8 waves). Block owns 16 consecutive hidden
// units -> 64 gate cols, gate-major (Ntile == gate). Flat flag barrier
// (1 cache line per block, no atomics). xg prefetched before the flag wait.
__global__ __launch_bounds__(512) void k_rec(
    const float* __restrict__ xg,                     // [MC][4096] chunk gates
    const u16* __restrict__ Whi, const u16* __restrict__ Wlo,  // [4096][1024]
    u16* __restrict__ hb_hi, u16* __restrict__ hb_lo, // [2][64][1024]
    float* __restrict__ cb,                           // [64][1024]
    u16* __restrict__ hs_hi, u16* __restrict__ hs_lo, // [MC][1024] or null
    float* __restrict__ hfinal,                       // [64][1024] or null
    u32* __restrict__ flags, int t0)                  // 64 flags, 64B apart
{
  __shared__ float sg[64][68];   // recurrent gate partials [batch][gatecol]
  __shared__ float sx[64][68];   // xg staging               [batch][gatecol]

  const int tid = threadIdx.x;
  const int lane = tid & 63, wv = tid >> 6;        // 8 waves
  const int l15 = lane & 15, l4 = lane >> 4;
  const int u0 = blockIdx.x * 16;

  // wave tiles: Mtile = wv&3 (batch), gates nt0, nt0+1
  const int mt = wv & 3;
  const int nt0 = (wv >> 2) * 2;

  // A fragment offset into h planes: m = mt*16+l15, k = kc*32 + l4*8
  const int a_off = (mt * 16 + l15) * 1024 + l4 * 8;

  // B fragments: col l15 of gate nt -> Whh row nt*1024 + u0 + l15
  const u16* bph0 = Whi + (size_t)(nt0 * 1024 + u0 + l15) * 1024 + l4 * 8;
  const u16* bpl0 = Wlo + (size_t)(nt0 * 1024 + u0 + l15) * 1024 + l4 * 8;
  const u16* bph1 = Whi + (size_t)((nt0 + 1) * 1024 + u0 + l15) * 1024 + l4 * 8;
  const u16* bpl1 = Wlo + (size_t)((nt0 + 1) * 1024 + u0 + l15) * 1024 + l4 * 8;

  // pointwise cells: (bA, uu) and (bA+32, uu)
  const int bA = tid >> 4, uu = tid & 15;
  float c0 = cb[bA * 1024 + u0 + uu];
  float c1 = cb[(bA + 32) * 1024 + u0 + uu];

  // xg prefetch: grp = tid>>4 reads segments s = grp*8+i ; b = grp*2+(i>>2), g = i&3
  const int grp = tid >> 4, lane16 = tid & 15;
  const float* xp0 = xg + (size_t)(grp * 2 * TC) * G4 + u0 + lane16;
  const float* xp1 = xp0 + (size_t)TC * G4;

  for (int tt = 0; tt < TC; ++tt) {
    const int t = t0 + tt;
    const int rb = (t & 1) << 16;   // h_{t-1} plane base (elements)
    const int wb = 65536 - rb;      // h_t plane base

    // ---- prefetch this step's xg (overlaps flag wait + MFMA) ----
    float px[8];
    {
      const float* p0 = xp0 + (size_t)tt * G4;
      const float* p1 = xp1 + (size_t)tt * G4;
#pragma unroll
      for (int g = 0; g < 4; ++g) {
        px[g] = p0[g * 1024];
        px[4 + g] = p1[g * 1024];
      }
    }

    // ---- wait for all blocks' h_{t-1} (flat flag barrier) ----
    if (tt > 0) {
      if (wv == 0) {
        const u32* fp = flags + lane * 16;
        while (__hip_atomic_load(fp, __ATOMIC_RELAXED, __HIP_MEMORY_SCOPE_AGENT) < (u32)tt)
          __builtin_amdgcn_s_sleep(1);
      }
      __syncthreads();
      __threadfence();
    }

    // ---- recurrent matmul: gates += h_{t-1} @ Whh^T (split precision) ----
    f32x4 acc0 = {}, acc1 = {};
#pragma unroll 8
    for (int kc = 0; kc < 32; ++kc) {
      int ka = rb + a_off + kc * 32;
      u16x8 ah = *(const u16x8*)(hb_hi + ka);
      u16x8 al = *(const u16x8*)(hb_lo + ka);
      int ko = kc * 32;
      u16x8 bh0 = *(const u16x8*)(bph0 + ko);
      u16x8 bl0 = *(const u16x8*)(bpl0 + ko);
      u16x8 bh1 = *(const u16x8*)(bph1 + ko);
      u16x8 bl1 = *(const u16x8*)(bpl1 + ko);
      acc0 = mfma16(ah, bh0, acc0);
      acc0 = mfma16(al, bh0, acc0);
      acc0 = mfma16(ah, bl0, acc0);
      acc1 = mfma16(ah, bh1, acc1);
      acc1 = mfma16(al, bh1, acc1);
      acc1 = mfma16(ah, bl1, acc1);
    }

    // ---- gather to LDS: C layout col=lane&15, row=(lane>>4)*4+reg ----
#pragma unroll
    for (int r = 0; r < 4; ++r) {
      int m = mt * 16 + l4 * 4 + r;
      sg[m][nt0 * 16 + l15] = acc0[r];
      sg[m][(nt0 + 1) * 16 + l15] = acc1[r];
    }
#pragma unroll
    for (int i = 0; i < 8; ++i)
      sx[grp * 2 + (i >> 2)][(i & 3) * 16 + lane16] = px[i];
    __syncthreads();

    // ---- pointwise: 2 cells per thread, c stays in registers ----
#pragma unroll
    for (int e = 0; e < 2; ++e) {
      int b = bA + e * 32;
      float gi = sg[b][uu] + sx[b][uu];
      float gf = sg[b][16 + uu] + sx[b][16 + uu];
      float gg = sg[b][32 + uu] + sx[b][32 + uu];
      float go = sg[b][48 + uu] + sx[b][48 + uu];
      float c = e ? c1 : c0;
      c = sigmoidf_(gf) * c + sigmoidf_(gi) * tanhf(gg);
      float h = sigmoidf_(go) * tanhf(c);
      if (e) c1 = c; else c0 = c;
      u16 hh = f2bf(h), hl = f2bf(h - bf2f(hh));
      int ho = b * 1024 + u0 + uu;
      hb_hi[wb + ho] = hh;
      hb_lo[wb + ho] = hl;
      if (hs_hi) {
        size_t so = (size_t)(b * TC + tt) * 1024 + u0 + uu;
        hs_hi[so] = hh;
        hs_lo[so] = hl;
      }
      if (hfinal && t == T_ - 1) hfinal[ho] = h;
    }

    // ---- release: h_t visible, then raise own flag ----
    __threadfence();
    __syncthreads();
    if (tid == 0)
      __hip_atomic_store(flags + blockIdx.x * 16, (u32)(tt + 1),
                         __ATOMIC_RELEASE, __HIP_MEMORY_SCOPE_AGENT);
  }

  cb[bA * 1024 + u0 + uu] = c0;
  cb[(bA + 32) * 1024 + u0 + uu] = c1;
}

// ---------- MLP (fp32 vector) ----------
__global__ void k_fc(const float* __restrict__ in, const float* __restrict__ W,
                     const float* __restrict__ bias, float* __restrict__ out,
                     int K, int N, int relu) {
  int b = blockIdx.x;
  int n = blockIdx.y * 256 + threadIdx.x;
  if (n >= N) return;
  const float4* wr = (const float4*)(W + (size_t)n * K);
  const float4* xr = (const float4*)(in + (size_t)b * K);
  float s = 0.f;
  for (int k = 0; k < K / 4; ++k) {
    float4 w = wr[k], x = xr[k];
    s += w.x * x.x + w.y * x.y + w.z * x.z + w.w * x.w;
  }
  s += bias[n];
  if (relu) s = fmaxf(s, 0.f);
  out[(size_t)b * N + n] = s;
}

__global__ void k_out(const float* __restrict__ z, const float* __restrict__ W3,
                      const float* __restrict__ b3, float* __restrict__ outp) {
  int b = blockIdx.x;
  int lane = threadIdx.x;  // 64
  const float4* wr = (const float4*)W3;
  const float4* xr = (const float4*)(z + b * 512);
  float s = 0.f;
  for (int k = lane; k < 128; k += 64) {
    float4 w = wr[k], x = xr[k];
    s += w.x * x.x + w.y * x.y + w.z * x.z + w.w * x.w;
  }
  for (int off = 32; off; off >>= 1) s += __shfl_down(s, off);
  if (lane == 0) outp[b] = s + b3[0];
}

// ---------- launch ----------
extern "C" void kernel_launch(void* const* d_in, const int* in_sizes, int n_in,
                              void* d_out, int out_size, void* d_ws, size_t ws_size,
                              hipStream_t stream) {
  (void)in_sizes; (void)n_in; (void)out_size; (void)ws_size;
  const float* xx  = (const float*)d_in[0];
  const float* W10 = (const float*)d_in[1];
  const float* b10i = (const float*)d_in[2];
  const float* b10h = (const float*)d_in[3];
  const float* W11 = (const float*)d_in[4];
  const float* b11i = (const float*)d_in[5];
  const float* b11h = (const float*)d_in[6];
  const float* W20 = (const float*)d_in[7];
  const float* Wh0 = (const float*)d_in[8];
  const float* b20i = (const float*)d_in[9];
  const float* b20h = (const float*)d_in[10];
  const float* W21 = (const float*)d_in[11];
  const float* Wh1 = (const float*)d_in[12];
  const float* b21i = (const float*)d_in[13];
  const float* b21h = (const float*)d_in[14];
  const float* mW1 = (const float*)d_in[15];
  const float* mb1 = (const float*)d_in[16];
  const float* mW2 = (const float*)d_in[17];
  const float* mb2 = (const float*)d_in[18];
  const float* mW3 = (const float*)d_in[19];
  const float* mb3 = (const float*)d_in[20];

  char* ws = (char*)d_ws;
  size_t o = 0;
  float* XG = (float*)(ws + o); o += (size_t)MC * G4 * 4;            // 64 MiB
  u16* Aah = (u16*)(ws + o); o += (size_t)MC * H_ * 2;               // ACT ping
  u16* Aal = (u16*)(ws + o); o += (size_t)MC * H_ * 2;
  u16* Abh = (u16*)(ws + o); o += (size_t)MC * H_ * 2;               // ACT pong
  u16* Abl = (u16*)(ws + o); o += (size_t)MC * H_ * 2;
  u16* XXh = (u16*)(ws + o); o += (size_t)MC * D_ * 2;
  u16* XXl = (u16*)(ws + o); o += (size_t)MC * D_ * 2;
  u16* W10h = (u16*)(ws + o); o += (size_t)G4 * D_ * 2;
  u16* W10l = (u16*)(ws + o); o += (size_t)G4 * D_ * 2;
  u16* W11h = (u16*)(ws + o); o += (size_t)G4 * H_ * 2;
  u16* W11l = (u16*)(ws + o); o += (size_t)G4 * H_ * 2;
  u16* W20h = (u16*)(ws + o); o += (size_t)G4 * H_ * 2;
  u16* W20l = (u16*)(ws + o); o += (size_t)G4 * H_ * 2;
  u16* Wh0h = (u16*)(ws + o); o += (size_t)G4 * H_ * 2;
  u16* Wh0l = (u16*)(ws + o); o += (size_t)G4 * H_ * 2;
  u16* W21h = (u16*)(ws + o); o += (size_t)G4 * H_ * 2;
  u16* W21l = (u16*)(ws + o); o += (size_t)G4 * H_ * 2;
  u16* Wh1h = (u16*)(ws + o); o += (size_t)G4 * H_ * 2;
  u16* Wh1l = (u16*)(ws + o); o += (size_t)G4 * H_ * 2;
  float* bs0 = (float*)(ws + o); o += G4 * 4;
  float* bs1 = (float*)(ws + o); o += G4 * 4;
  float* bs2 = (float*)(ws + o); o += G4 * 4;
  float* bs3 = (float*)(ws + o); o += G4 * 4;
  // state region (zeroed once per launch, contiguous)
  char* ST = ws + o;
  u16* hb0h = (u16*)(ws + o); o += 2 * B_ * H_ * 2;
  u16* hb0l = (u16*)(ws + o); o += 2 * B_ * H_ * 2;
  u16* hb1h = (u16*)(ws + o); o += 2 * B_ * H_ * 2;
  u16* hb1l = (u16*)(ws + o); o += 2 * B_ * H_ * 2;
  float* cb0 = (float*)(ws + o); o += B_ * H_ * 4;
  float* cb1 = (float*)(ws + o); o += B_ * H_ * 4;
  u32* FLG = (u32*)(ws + o); o += 8 * RBLK * 16 * 4;   // 8 instances x 64 flags x 64B
  size_t stBytes = (size_t)((ws + o) - ST);
  float* FH = (float*)(ws + o); o += B_ * H_ * 4;
  float* Z1 = (float*)(ws + o); o += B_ * H_ * 4;
  float* Z2 = (float*)(ws + o); o += B_ * 512 * 4;

  // --- one-time weight/bias prep ---
  k_split<<<(G4 * D_ / 4 + 255) / 256, 256, 0, stream>>>(W10, W10h, W10l, G4 * D_ / 4);
  k_split<<<(G4 * H_ / 4 + 255) / 256, 256, 0, stream>>>(W11, W11h, W11l, G4 * H_ / 4);
  k_split<<<(G4 * H_ / 4 + 255) / 256, 256, 0, stream>>>(W20, W20h, W20l, G4 * H_ / 4);
  k_split<<<(G4 * H_ / 4 + 255) / 256, 256, 0, stream>>>(Wh0, Wh0h, Wh0l, G4 * H_ / 4);
  k_split<<<(G4 * H_ / 4 + 255) / 256, 256, 0, stream>>>(W21, W21h, W21l, G4 * H_ / 4);
  k_split<<<(G4 * H_ / 4 + 255) / 256, 256, 0, stream>>>(Wh1, Wh1h, Wh1l, G4 * H_ / 4);
  k_addvec<<<16, 256, 0, stream>>>(b10i, b10h, bs0, G4);
  k_addvec<<<16, 256, 0, stream>>>(b11i, b11h, bs1, G4);
  k_addvec<<<16, 256, 0, stream>>>(b20i, b20h, bs2, G4);
  k_addvec<<<16, 256, 0, stream>>>(b21i, b21h, bs3, G4);
  hipMemsetAsync(ST, 0, stBytes, stream);

  dim3 gg(MC / 128, G4 / 128);
  const int pwBlocks = MC * H_ / 256;

  for (int c = 0; c < NCHUNK; ++c) {
    int t0 = c * TC;
    k_split_x<<<(MC * (D_ / 4) + 255) / 256, 256, 0, stream>>>(xx, XXh, XXl, t0);
    // l1 layer 0
    k_gemm3<<<gg, 256, 0, stream>>>(XXh, XXl, W10h, W10l, bs0, XG, MC, G4, D_);
    k_pw<<<pwBlocks, 256, 0, stream>>>(XG, Aah, Aal);
    // l1 layer 1
    k_gemm3<<<gg, 256, 0, stream>>>(Aah, Aal, W11h, W11l, bs1, XG, MC, G4, H_);
    k_pw<<<pwBlocks, 256, 0, stream>>>(XG, Abh, Abl);
    // l2 layer 0
    k_gemm3<<<gg, 256, 0, stream>>>(Abh, Abl, W20h, W20l, bs2, XG, MC, G4, H_);
    k_rec<<<RBLK, 512, 0, stream>>>(XG, Wh0h, Wh0l, hb0h, hb0l, cb0,
                                    Aah, Aal, nullptr, FLG + (c * 2) * RBLK * 16, t0);
    // l2 layer 1
    k_gemm3<<<gg, 256, 0, stream>>>(Aah, Aal, W21h, W21l, bs3, XG, MC, G4, H_);
    k_rec<<<RBLK, 512, 0, stream>>>(XG, Wh1h, Wh1l, hb1h, hb1l, cb1,
                                    nullptr, nullptr, FH, FLG + (c * 2 + 1) * RBLK * 16, t0);
  }

  // MLP
  k_fc<<<dim3(B_, 4), 256, 0, stream>>>(FH, mW1, mb1, Z1, H_, H_, 1);
  k_fc<<<dim3(B_, 2), 256, 0, stream>>>(Z1, mW2, mb2, Z2, H_, 512, 1);
  k_out<<<B_, 64, 0, stream>>>(Z2, mW3, mb3, (float*)d_out);
}

// Round 4
// 12477.820 us; speedup vs baseline: 3.2852x; 2.7219x over previous
//
#include <hip/hip_runtime.h>

typedef unsigned short u16;
typedef unsigned int u32;
typedef u16 u16x8 __attribute__((ext_vector_type(8)));
typedef u16 u16x4 __attribute__((ext_vector_type(4)));
typedef __bf16 bf16x8 __attribute__((ext_vector_type(8)));
typedef float f32x4 __attribute__((ext_vector_type(4)));
typedef float f32x2 __attribute__((ext_vector_type(2)));

#define B_ 64
#define T_ 256
#define D_ 256
#define H_ 1024
#define G4 4096
#define TC 64            // timesteps per chunk
#define MC 4096          // rows per chunk (B_*TC)
#define NCHUNK 4
#define RBLK 128         // k_rec blocks: 64 unit-groups x 2 batch-halves

// ---------- helpers ----------
__device__ __forceinline__ u16 f2bf(float x) {
  u32 u = __builtin_bit_cast(u32, x);
  u += 0x7fffu + ((u >> 16) & 1u);
  return (u16)(u >> 16);
}
__device__ __forceinline__ float bf2f(u16 h) {
  u32 u = ((u32)h) << 16;
  return __builtin_bit_cast(float, u);
}
__device__ __forceinline__ float sigmoidf_(float x) { return 1.f / (1.f + __expf(-x)); }

__device__ __forceinline__ f32x4 mfma16(u16x8 a, u16x8 b, f32x4 c) {
  return __builtin_amdgcn_mfma_f32_16x16x32_bf16(
      __builtin_bit_cast(bf16x8, a), __builtin_bit_cast(bf16x8, b), c, 0, 0, 0);
}

__device__ __forceinline__ void gl2lds16(const u16* g, u16* l) {
  __builtin_amdgcn_global_load_lds(
      (const __attribute__((address_space(1))) u32*)(const void*)g,
      (__attribute__((address_space(3))) u32*)(void*)l, 16, 0, 0);
}

// device-coherent (cross-XCD) 16B load / 4B store, bypassing non-coherent L2
__device__ __forceinline__ u16x8 load16_cc(const u16* p) {
  u16x8 v;
  asm volatile("global_load_dwordx4 %0, %1, off sc0 sc1" : "=v"(v) : "v"(p));
  return v;
}
__device__ __forceinline__ void store4_cc(u16* p, u32 v) {
  asm volatile("global_store_dword %0, %1, off sc0 sc1" :: "v"(p), "v"(v) : "memory");
}
__device__ __forceinline__ void waitcnt0() {
  asm volatile("s_waitcnt vmcnt(0)" ::: "memory");
}

// ---------- split fp32 -> (hi, lo) bf16 planes ----------
__global__ void k_split(const float* __restrict__ src, u16* __restrict__ hi,
                        u16* __restrict__ lo, int n4) {
  int i = blockIdx.x * 256 + threadIdx.x;
  if (i >= n4) return;
  const float4* s4 = (const float4*)src;
  float4 v = s4[i];
  u16 h0 = f2bf(v.x), h1 = f2bf(v.y), h2 = f2bf(v.z), h3 = f2bf(v.w);
  u16x4 hv = {h0, h1, h2, h3};
  u16x4 lv = {f2bf(v.x - bf2f(h0)), f2bf(v.y - bf2f(h1)),
              f2bf(v.z - bf2f(h2)), f2bf(v.w - bf2f(h3))};
  *(u16x4*)(hi + 4 * (size_t)i) = hv;
  *(u16x4*)(lo + 4 * (size_t)i) = lv;
}

// gather one time-chunk of xx ([B,T,D] -> [B*TC, D]) and split planes
__global__ void k_split_x(const float* __restrict__ xx, u16* __restrict__ hi,
                          u16* __restrict__ lo, int t0) {
  int i = blockIdx.x * 256 + threadIdx.x;   // over MC * D_/4
  if (i >= MC * (D_ / 4)) return;
  int row = i >> 6, c4 = i & 63;
  int b = row >> 6, tc = row & 63;
  const float4* s4 = (const float4*)xx;
  float4 v = s4[(size_t)(b * T_ + t0 + tc) * (D_ / 4) + c4];
  u16 h0 = f2bf(v.x), h1 = f2bf(v.y), h2 = f2bf(v.z), h3 = f2bf(v.w);
  u16x4 hv = {h0, h1, h2, h3};
  u16x4 lv = {f2bf(v.x - bf2f(h0)), f2bf(v.y - bf2f(h1)),
              f2bf(v.z - bf2f(h2)), f2bf(v.w - bf2f(h3))};
  *(u16x4*)(hi + 4 * (size_t)i) = hv;
  *(u16x4*)(lo + 4 * (size_t)i) = lv;
}

__global__ void k_addvec(const float* __restrict__ a, const float* __restrict__ b,
                         float* __restrict__ o, int n) {
  int i = blockIdx.x * 256 + threadIdx.x;
  if (i < n) o[i] = a[i] + b[i];
}

// ---------- split-precision GEMM: C[M,N] = A[M,K] * B[N,K]^T + bias (fp32 out) ----
// rec=0: standard C[m][n] layout.  rec=1: k_rec-friendly layout
//   C[((ug*2+ph)*64 + t)*2048 + g*512 + b*16 + u]   (m = B*64+t, n = g*1024+ug*16+u, B=ph*32+b)
__global__ __launch_bounds__(256, 2) void k_gemm3(
    const u16* __restrict__ Ah, const u16* __restrict__ Al,
    const u16* __restrict__ Bh, const u16* __restrict__ Bl,
    const float* __restrict__ bias, float* __restrict__ C,
    int M, int N, int K, int rec)
{
  __shared__ __attribute__((aligned(16))) u16 sAh[4096];
  __shared__ __attribute__((aligned(16))) u16 sAl[4096];
  __shared__ __attribute__((aligned(16))) u16 sBh[4096];
  __shared__ __attribute__((aligned(16))) u16 sBl[4096];

  const int tid = threadIdx.x;
  const int lane = tid & 63;
  const int wv = tid >> 6;
  const int wm = wv & 1, wn = wv >> 1;
  const int m0 = blockIdx.x * 128;
  const int n0 = blockIdx.y * 128;

  const int r0 = tid >> 2;
  const int kg = (tid & 3) ^ (r0 & 3);
  const size_t aoff0 = (size_t)(m0 + r0) * K + kg * 8;
  const size_t aoff1 = (size_t)(m0 + r0 + 64) * K + kg * 8;
  const size_t boff0 = (size_t)(n0 + r0) * K + kg * 8;
  const size_t boff1 = (size_t)(n0 + r0 + 64) * K + kg * 8;
  const int lb0 = wv * 512;
  const int lb1 = 2048 + wv * 512;

  const int l15 = lane & 15, l4 = lane >> 4;
  int afo[4], bfo[4];
#pragma unroll
  for (int mt = 0; mt < 4; ++mt) {
    int r = wm * 64 + mt * 16 + l15;
    afo[mt] = (r * 4 + (l4 ^ (r & 3))) * 8;
  }
#pragma unroll
  for (int nt = 0; nt < 4; ++nt) {
    int r = wn * 64 + nt * 16 + l15;
    bfo[nt] = (r * 4 + (l4 ^ (r & 3))) * 8;
  }

  f32x4 acc[4][4] = {};

  for (int k0 = 0; k0 < K; k0 += 32) {
    __syncthreads();
    gl2lds16(Ah + aoff0 + k0, &sAh[lb0]);
    gl2lds16(Ah + aoff1 + k0, &sAh[lb1]);
    gl2lds16(Al + aoff0 + k0, &sAl[lb0]);
    gl2lds16(Al + aoff1 + k0, &sAl[lb1]);
    gl2lds16(Bh + boff0 + k0, &sBh[lb0]);
    gl2lds16(Bh + boff1 + k0, &sBh[lb1]);
    gl2lds16(Bl + boff0 + k0, &sBl[lb0]);
    gl2lds16(Bl + boff1 + k0, &sBl[lb1]);
    __syncthreads();

    u16x8 a_h[4], a_l[4], b_h[4], b_l[4];
#pragma unroll
    for (int i = 0; i < 4; ++i) {
      a_h[i] = *(const u16x8*)&sAh[afo[i]];
      a_l[i] = *(const u16x8*)&sAl[afo[i]];
      b_h[i] = *(const u16x8*)&sBh[bfo[i]];
      b_l[i] = *(const u16x8*)&sBl[bfo[i]];
    }
#pragma unroll
    for (int mt = 0; mt < 4; ++mt)
#pragma unroll
      for (int nt = 0; nt < 4; ++nt) {
        acc[mt][nt] = mfma16(a_h[mt], b_h[nt], acc[mt][nt]);
        acc[mt][nt] = mfma16(a_l[mt], b_h[nt], acc[mt][nt]);
        acc[mt][nt] = mfma16(a_h[mt], b_l[nt], acc[mt][nt]);
      }
  }

  if (!rec) {
#pragma unroll
    for (int mt = 0; mt < 4; ++mt) {
      int mr = m0 + wm * 64 + mt * 16 + l4 * 4;
#pragma unroll
      for (int nt = 0; nt < 4; ++nt) {
        int nc = n0 + wn * 64 + nt * 16 + l15;
        float bv = bias[nc];
#pragma unroll
        for (int r = 0; r < 4; ++r)
          C[(size_t)(mr + r) * N + nc] = acc[mt][nt][r] + bv;
      }
    }
  } else {
#pragma unroll
    for (int mt = 0; mt < 4; ++mt) {
      int mr = m0 + wm * 64 + mt * 16 + l4 * 4;
      int Bb = mr >> 6, tloc = mr & 63;
      int ph = Bb >> 5, b = Bb & 31;
#pragma unroll
      for (int nt = 0; nt < 4; ++nt) {
        int nc = n0 + wn * 64 + nt * 16 + l15;
        float bv = bias[nc];
        int g = nc >> 10, U = nc & 1023;
        int ug = U >> 4, u = U & 15;
        size_t base = ((size_t)(((ug * 2 + ph) * 64 + tloc) * 4 + g)) * 512 + b * 16 + u;
#pragma unroll
        for (int r = 0; r < 4; ++r)
          C[base + (size_t)r * 2048] = acc[mt][nt][r] + bv;
      }
    }
  }
}

// ---------- l1 pointwise on one chunk ----------
__global__ void k_pw(const float* __restrict__ xg, u16* __restrict__ hhi,
                     u16* __restrict__ hlo) {
  int idx = blockIdx.x * 256 + threadIdx.x;  // MC*H_ threads
  int r = idx >> 10, j = idx & 1023;
  const float* g = xg + (size_t)r * G4;
  float cc = sigmoidf_(g[j]) * tanhf(g[2048 + j]);
  float h = sigmoidf_(g[3072 + j]) * tanhf(cc);
  u16 hh = f2bf(h);
  hhi[idx] = hh;
  hlo[idx] = f2bf(h - bf2f(hh));
}

// ---------- persistent recurrent LSTM, one time-chunk ----------
// 128 blocks x 256 threads. Block = (unit-group ug: 16 units) x (batch-half ph: 32 rows).
// h hi/lo staged into LDS each step via sc0sc1 loads (L2 never polluted/invalidated);
// Whh read with normal cached loads -> L2-resident across all steps. No cache fences.
__global__ __launch_bounds__(256, 1) void k_rec(
    const float* __restrict__ xg,                     // rec layout, 64 MB chunk
    const u16* __restrict__ Whi, const u16* __restrict__ Wlo,  // [4096][1024]
    u16* __restrict__ hb_hi, u16* __restrict__ hb_lo, // [2][64][1024] (sc1 domain)
    float* __restrict__ cb,                           // [64][1024]
    u16* __restrict__ hs_hi, u16* __restrict__ hs_lo, // [MC][1024] or null
    float* __restrict__ hfinal,                       // [64][1024] or null
    u32* __restrict__ flags, int t0)                  // RBLK flags, 64B apart
{
  __shared__ __attribute__((aligned(16))) u16 sH[66048];  // [2][32][1032]
  __shared__ float sg[32 * 72];                           // [32 b][4 g x 18]

  const int tid = threadIdx.x;
  const int lane = tid & 63, wv = tid >> 6;
  const int l15 = lane & 15, l4 = lane >> 4;
  const int ug = blockIdx.x >> 1, ph = blockIdx.x & 1;
  const int u0 = ug * 16, bb0 = ph * 32;

  // wave tiles: mt = batch 16-row tile (0/1), np = gate pair (0/1)
  const int mt = wv & 1, np = wv >> 1;
  const int g0 = np * 2;

  // B fragment pointers (normal cached loads; L2-resident)
  const u16* bph0 = Whi + (size_t)(g0 * 1024 + u0 + l15) * 1024 + l4 * 8;
  const u16* bpl0 = Wlo + (size_t)(g0 * 1024 + u0 + l15) * 1024 + l4 * 8;
  const u16* bph1 = Whi + (size_t)((g0 + 1) * 1024 + u0 + l15) * 1024 + l4 * 8;
  const u16* bpl1 = Wlo + (size_t)((g0 + 1) * 1024 + u0 + l15) * 1024 + l4 * 8;

  // LDS A-fragment base (elements): plane p*33024 + row*1032 + l4*8
  const int arow = (mt * 16 + l15) * 1032 + l4 * 8;

  // staging map: per thread k16 fixed; 32 chunks k=0..31: plane k>>4, row (2k+tid7)&31
  const int k16 = tid & 127, tid7 = tid >> 7;

  // pointwise cells: batch b, units up, up+1
  const int b = tid >> 3, up = (tid & 7) * 2;
  const int hoff = (bb0 + b) * 1024 + u0 + up;
  f32x2 cc = *(const f32x2*)(cb + hoff);

  const float* xgb = xg + (size_t)blockIdx.x * TC * 2048 + b * 16 + up;

  for (int tt = 0; tt < TC; ++tt) {
    const int t = t0 + tt;
    const int rbase = (t & 1) << 16;   // h_{t-1} plane (elements)
    const int wbase = 65536 - rbase;   // h_t plane

    // ---- prefetch this step's xg (issues before the flag wait) ----
    const float* xa = xgb + (size_t)tt * 2048;
    f32x2 px0, px1, px2, px3;
    asm volatile("global_load_dwordx2 %0, %1, off" : "=v"(px0) : "v"(xa));
    asm volatile("global_load_dwordx2 %0, %1, off" : "=v"(px1) : "v"(xa + 512));
    asm volatile("global_load_dwordx2 %0, %1, off" : "=v"(px2) : "v"(xa + 1024));
    asm volatile("global_load_dwordx2 %0, %1, off" : "=v"(px3) : "v"(xa + 1536));

    // ---- wait for all blocks to have produced h_{t-1} ----
    if (tt > 0) {
      if (wv == 0) {
        const u32* f0 = flags + lane * 16;
        const u32* f1 = flags + 1024 + lane * 16;
        for (;;) {
          u32 a = __hip_atomic_load(f0, __ATOMIC_RELAXED, __HIP_MEMORY_SCOPE_AGENT);
          u32 bfl = __hip_atomic_load(f1, __ATOMIC_RELAXED, __HIP_MEMORY_SCOPE_AGENT);
          if (a >= (u32)tt && bfl >= (u32)tt) break;
          __builtin_amdgcn_s_sleep(1);
        }
      }
      __syncthreads();
    }

    // ---- stage h_{t-1} (this half's 32 batches, hi+lo) into LDS ----
    {
      u16x8 tmp[32];
#pragma unroll
      for (int k = 0; k < 32; ++k) {
        int rw = (2 * k + tid7) & 31;
        const u16* sp = (k >= 16 ? hb_lo : hb_hi) + rbase + (bb0 + rw) * 1024 + k16 * 8;
        tmp[k] = load16_cc(sp);
      }
      waitcnt0();
#pragma unroll
      for (int k = 0; k < 32; ++k) {
        int rw = (2 * k + tid7) & 31;
        *(u16x8*)&sH[(k >> 4) * 33024 + rw * 1032 + k16 * 8] = tmp[k];
      }
    }
    __syncthreads();

    // ---- recurrent matmul: gates += h_{t-1} @ Whh^T (split precision) ----
    f32x4 acc0 = {}, acc1 = {};
#pragma unroll 8
    for (int kc = 0; kc < 32; ++kc) {
      int ko = kc * 32;
      u16x8 ah = *(const u16x8*)&sH[arow + ko];
      u16x8 al = *(const u16x8*)&sH[33024 + arow + ko];
      u16x8 bh0 = *(const u16x8*)(bph0 + ko);
      u16x8 bl0 = *(const u16x8*)(bpl0 + ko);
      u16x8 bh1 = *(const u16x8*)(bph1 + ko);
      u16x8 bl1 = *(const u16x8*)(bpl1 + ko);
      acc0 = mfma16(ah, bh0, acc0);
      acc0 = mfma16(al, bh0, acc0);
      acc0 = mfma16(ah, bl0, acc0);
      acc1 = mfma16(ah, bh1, acc1);
      acc1 = mfma16(al, bh1, acc1);
      acc1 = mfma16(ah, bl1, acc1);
    }

    // ---- gather gate partials to LDS (C layout: col=l15, row=l4*4+r) ----
#pragma unroll
    for (int r = 0; r < 4; ++r) {
      int m = mt * 16 + l4 * 4 + r;
      sg[m * 72 + g0 * 18 + l15] = acc0[r];
      sg[m * 72 + (g0 + 1) * 18 + l15] = acc1[r];
    }
    __syncthreads();

    // ---- pointwise: 2 adjacent-unit cells per thread ----
    {
      waitcnt0();  // px ready (usually already drained by staging wait)
      const float* srow = sg + b * 72;
      float gi0 = srow[up] + px0[0],      gi1 = srow[up + 1] + px0[1];
      float gf0 = srow[18 + up] + px1[0], gf1 = srow[18 + up + 1] + px1[1];
      float gg0 = srow[36 + up] + px2[0], gg1 = srow[36 + up + 1] + px2[1];
      float go0 = srow[54 + up] + px3[0], go1 = srow[54 + up + 1] + px3[1];
      float c0 = sigmoidf_(gf0) * cc[0] + sigmoidf_(gi0) * tanhf(gg0);
      float c1 = sigmoidf_(gf1) * cc[1] + sigmoidf_(gi1) * tanhf(gg1);
      float h0 = sigmoidf_(go0) * tanhf(c0);
      float h1 = sigmoidf_(go1) * tanhf(c1);
      cc[0] = c0; cc[1] = c1;
      u16 h0h = f2bf(h0), h1h = f2bf(h1);
      u32 hiPair = (u32)h0h | ((u32)h1h << 16);
      u32 loPair = (u32)f2bf(h0 - bf2f(h0h)) | ((u32)f2bf(h1 - bf2f(h1h)) << 16);
      store4_cc(hb_hi + wbase + hoff, hiPair);
      store4_cc(hb_lo + wbase + hoff, loPair);
      if (hs_hi) {
        size_t so = ((size_t)(bb0 + b) * TC + tt) * 1024 + u0 + up;
        *(u32*)(hs_hi + so) = hiPair;
        *(u32*)(hs_lo + so) = loPair;
      }
      if (hfinal && t == T_ - 1) *(f32x2*)(hfinal + hoff) = cc * 0.f + (f32x2){h0, h1};
    }

    // ---- release: drain h stores, then raise own flag ----
    waitcnt0();
    __syncthreads();
    if (tid == 0)
      __hip_atomic_store(flags + blockIdx.x * 16, (u32)(tt + 1),
                         __ATOMIC_RELEASE, __HIP_MEMORY_SCOPE_AGENT);
  }

  *(f32x2*)(cb + hoff) = cc;
}

// ---------- MLP (fp32 vector) ----------
__global__ void k_fc(const float* __restrict__ in, const float* __restrict__ W,
                     const float* __restrict__ bias, float* __restrict__ out,
                     int K, int N, int relu) {
  int b = blockIdx.x;
  int n = blockIdx.y * 256 + threadIdx.x;
  if (n >= N) return;
  const float4* wr = (const float4*)(W + (size_t)n * K);
  const float4* xr = (const float4*)(in + (size_t)b * K);
  float s = 0.f;
  for (int k = 0; k < K / 4; ++k) {
    float4 w = wr[k], x = xr[k];
    s += w.x * x.x + w.y * x.y + w.z * x.z + w.w * x.w;
  }
  s += bias[n];
  if (relu) s = fmaxf(s, 0.f);
  out[(size_t)b * N + n] = s;
}

__global__ void k_out(const float* __restrict__ z, const float* __restrict__ W3,
                      const float* __restrict__ b3, float* __restrict__ outp) {
  int b = blockIdx.x;
  int lane = threadIdx.x;  // 64
  const float4* wr = (const float4*)W3;
  const float4* xr = (const float4*)(z + b * 512);
  float s = 0.f;
  for (int k = lane; k < 128; k += 64) {
    float4 w = wr[k], x = xr[k];
    s += w.x * x.x + w.y * x.y + w.z * x.z + w.w * x.w;
  }
  for (int off = 32; off; off >>= 1) s += __shfl_down(s, off);
  if (lane == 0) outp[b] = s + b3[0];
}

// ---------- launch ----------
extern "C" void kernel_launch(void* const* d_in, const int* in_sizes, int n_in,
                              void* d_out, int out_size, void* d_ws, size_t ws_size,
                              hipStream_t stream) {
  (void)in_sizes; (void)n_in; (void)out_size; (void)ws_size;
  const float* xx  = (const float*)d_in[0];
  const float* W10 = (const float*)d_in[1];
  const float* b10i = (const float*)d_in[2];
  const float* b10h = (const float*)d_in[3];
  const float* W11 = (const float*)d_in[4];
  const float* b11i = (const float*)d_in[5];
  const float* b11h = (const float*)d_in[6];
  const float* W20 = (const float*)d_in[7];
  const float* Wh0 = (const float*)d_in[8];
  const float* b20i = (const float*)d_in[9];
  const float* b20h = (const float*)d_in[10];
  const float* W21 = (const float*)d_in[11];
  const float* Wh1 = (const float*)d_in[12];
  const float* b21i = (const float*)d_in[13];
  const float* b21h = (const float*)d_in[14];
  const float* mW1 = (const float*)d_in[15];
  const float* mb1 = (const float*)d_in[16];
  const float* mW2 = (const float*)d_in[17];
  const float* mb2 = (const float*)d_in[18];
  const float* mW3 = (const float*)d_in[19];
  const float* mb3 = (const float*)d_in[20];

  char* ws = (char*)d_ws;
  size_t o = 0;
  float* XG = (float*)(ws + o); o += (size_t)MC * G4 * 4;            // 64 MiB
  u16* Aah = (u16*)(ws + o); o += (size_t)MC * H_ * 2;               // ACT ping
  u16* Aal = (u16*)(ws + o); o += (size_t)MC * H_ * 2;
  u16* Abh = (u16*)(ws + o); o += (size_t)MC * H_ * 2;               // ACT pong
  u16* Abl = (u16*)(ws + o); o += (size_t)MC * H_ * 2;
  u16* XXh = (u16*)(ws + o); o += (size_t)MC * D_ * 2;
  u16* XXl = (u16*)(ws + o); o += (size_t)MC * D_ * 2;
  u16* W10h = (u16*)(ws + o); o += (size_t)G4 * D_ * 2;
  u16* W10l = (u16*)(ws + o); o += (size_t)G4 * D_ * 2;
  u16* W11h = (u16*)(ws + o); o += (size_t)G4 * H_ * 2;
  u16* W11l = (u16*)(ws + o); o += (size_t)G4 * H_ * 2;
  u16* W20h = (u16*)(ws + o); o += (size_t)G4 * H_ * 2;
  u16* W20l = (u16*)(ws + o); o += (size_t)G4 * H_ * 2;
  u16* Wh0h = (u16*)(ws + o); o += (size_t)G4 * H_ * 2;
  u16* Wh0l = (u16*)(ws + o); o += (size_t)G4 * H_ * 2;
  u16* W21h = (u16*)(ws + o); o += (size_t)G4 * H_ * 2;
  u16* W21l = (u16*)(ws + o); o += (size_t)G4 * H_ * 2;
  u16* Wh1h = (u16*)(ws + o); o += (size_t)G4 * H_ * 2;
  u16* Wh1l = (u16*)(ws + o); o += (size_t)G4 * H_ * 2;
  float* bs0 = (float*)(ws + o); o += G4 * 4;
  float* bs1 = (float*)(ws + o); o += G4 * 4;
  float* bs2 = (float*)(ws + o); o += G4 * 4;
  float* bs3 = (float*)(ws + o); o += G4 * 4;
  // state region (zeroed once per launch, contiguous)
  char* ST = ws + o;
  u16* hb0h = (u16*)(ws + o); o += 2 * B_ * H_ * 2;
  u16* hb0l = (u16*)(ws + o); o += 2 * B_ * H_ * 2;
  u16* hb1h = (u16*)(ws + o); o += 2 * B_ * H_ * 2;
  u16* hb1l = (u16*)(ws + o); o += 2 * B_ * H_ * 2;
  float* cb0 = (float*)(ws + o); o += B_ * H_ * 4;
  float* cb1 = (float*)(ws + o); o += B_ * H_ * 4;
  u32* FLG = (u32*)(ws + o); o += 8 * RBLK * 16 * 4;   // 8 instances x 128 flags x 64B
  size_t stBytes = (size_t)((ws + o) - ST);
  float* FH = (float*)(ws + o); o += B_ * H_ * 4;
  float* Z1 = (float*)(ws + o); o += B_ * H_ * 4;
  float* Z2 = (float*)(ws + o); o += B_ * 512 * 4;

  // --- one-time weight/bias prep ---
  k_split<<<(G4 * D_ / 4 + 255) / 256, 256, 0, stream>>>(W10, W10h, W10l, G4 * D_ / 4);
  k_split<<<(G4 * H_ / 4 + 255) / 256, 256, 0, stream>>>(W11, W11h, W11l, G4 * H_ / 4);
  k_split<<<(G4 * H_ / 4 + 255) / 256, 256, 0, stream>>>(W20, W20h, W20l, G4 * H_ / 4);
  k_split<<<(G4 * H_ / 4 + 255) / 256, 256, 0, stream>>>(Wh0, Wh0h, Wh0l, G4 * H_ / 4);
  k_split<<<(G4 * H_ / 4 + 255) / 256, 256, 0, stream>>>(W21, W21h, W21l, G4 * H_ / 4);
  k_split<<<(G4 * H_ / 4 + 255) / 256, 256, 0, stream>>>(Wh1, Wh1h, Wh1l, G4 * H_ / 4);
  k_addvec<<<16, 256, 0, stream>>>(b10i, b10h, bs0, G4);
  k_addvec<<<16, 256, 0, stream>>>(b11i, b11h, bs1, G4);
  k_addvec<<<16, 256, 0, stream>>>(b20i, b20h, bs2, G4);
  k_addvec<<<16, 256, 0, stream>>>(b21i, b21h, bs3, G4);
  hipMemsetAsync(ST, 0, stBytes, stream);

  dim3 gg(MC / 128, G4 / 128);
  const int pwBlocks = MC * H_ / 256;

  for (int c = 0; c < NCHUNK; ++c) {
    int t0 = c * TC;
    k_split_x<<<(MC * (D_ / 4) + 255) / 256, 256, 0, stream>>>(xx, XXh, XXl, t0);
    // l1 layer 0
    k_gemm3<<<gg, 256, 0, stream>>>(XXh, XXl, W10h, W10l, bs0, XG, MC, G4, D_, 0);
    k_pw<<<pwBlocks, 256, 0, stream>>>(XG, Aah, Aal);
    // l1 layer 1
    k_gemm3<<<gg, 256, 0, stream>>>(Aah, Aal, W11h, W11l, bs1, XG, MC, G4, H_, 0);
    k_pw<<<pwBlocks, 256, 0, stream>>>(XG, Abh, Abl);
    // l2 layer 0 (rec-layout gates)
    k_gemm3<<<gg, 256, 0, stream>>>(Abh, Abl, W20h, W20l, bs2, XG, MC, G4, H_, 1);
    k_rec<<<RBLK, 256, 0, stream>>>(XG, Wh0h, Wh0l, hb0h, hb0l, cb0,
                                    Aah, Aal, nullptr, FLG + (c * 2) * RBLK * 16, t0);
    // l2 layer 1 (rec-layout gates)
    k_gemm3<<<gg, 256, 0, stream>>>(Aah, Aal, W21h, W21l, bs3, XG, MC, G4, H_, 1);
    k_rec<<<RBLK, 256, 0, stream>>>(XG, Wh1h, Wh1l, hb1h, hb1l, cb1,
                                    nullptr, nullptr, FH, FLG + (c * 2 + 1) * RBLK * 16, t0);
  }

  // MLP
  k_fc<<<dim3(B_, 4), 256, 0, stream>>>(FH, mW1, mb1, Z1, H_, H_, 1);
  k_fc<<<dim3(B_, 2), 256, 0, stream>>>(Z1, mW2, mb2, Z2, H_, 512, 1);
  k_out<<<B_, 64, 0, stream>>>(Z2, mW3, mb3, (float*)d_out);
}